// Round 16
// baseline (153.706 us; speedup 1.0000x reference)
//
#include <hip/hip_runtime.h>
#include <hip/hip_bf16.h>

// Fused map-obs attention (Attention_5815385719367), MI355X/gfx950.
// R16: (a) attn: 24KB LDS (4-kb chunks) + __launch_bounds__(512,8) ->
// 4 blocks/CU x 8 waves = 32 waves/CU and an even 2-round makespan
// (was 48KB -> 3 blocks/CU, 2.67 uneven rounds). (b) reduce_oP+epilogue
// fused into one kernel (uint2 slice-reduce -> LDS -> Wo/LN), killing one
// launch + the agg round-trip. ks=32 kept (attn makespan > partial tax).
//
// ws layout (~40 MB; kslog auto-drops if ws_size is short):
//   qbf  [n_map][64] bf16 (pre-scaled by IT)
//   Kp   [n_obs/32][4][64][8] bf16, Vp [n_obs/32][2][64][8] bf16
//   pself[n_map] f32, gmT[32][n_map] f32
//   oP [ks][ntiles][32][32] bf16,  lP [ks][n_map] f32

typedef float f32x16 __attribute__((ext_vector_type(16)));
typedef short bf16x8 __attribute__((ext_vector_type(8)));
typedef unsigned int u32;

__device__ __forceinline__ u32 cvt_pk_bf16(float lo, float hi) {
    u32 r;
    asm("v_cvt_pk_bf16_f32 %0, %1, %2" : "=v"(r) : "v"(lo), "v"(hi));
    return r;
}
__device__ __forceinline__ void permswap32(u32& a, u32& b) {
    asm("v_permlane32_swap_b32 %0, %1" : "+v"(a), "+v"(b));
}

#define IT 0.18033688011112042f  // log2(e)/TEMPERATURE, T=8
#define LOG2E 1.44269504089f

// ---------------------------------------------------------------- prep ----
// 256 thr = 4 waves; wave handles 8 rows (32 rows/block), d-loop outer.
__global__ __launch_bounds__(256) void prep_kernel(
    const float* __restrict__ map_code, const float* __restrict__ obs_code,
    const float* __restrict__ Wq, const float* __restrict__ Wk,
    const float* __restrict__ Wv,
    __hip_bfloat16* __restrict__ qbf, __hip_bfloat16* __restrict__ Kp,
    __hip_bfloat16* __restrict__ Vp, float* __restrict__ pself,
    float* __restrict__ gmT, int n_map, int n_obs)
{
    __shared__ float xs[32 * 64];
    const int t = threadIdx.x;
    const int w = t >> 6;
    const int e = t & 63;
    const int r0 = blockIdx.x * 32;
    const int total = n_map + n_obs;

    // stage 32 rows of concat(map, obs), coalesced
    #pragma unroll
    for (int i = 0; i < 8; ++i) {
        const int idx = i * 256 + t;
        const int gr = r0 + (idx >> 6);
        const int col = idx & 63;
        float val = 0.0f;
        if (gr < n_map)      val = map_code[(size_t)gr * 64 + col];
        else if (gr < total) val = obs_code[(size_t)(gr - n_map) * 64 + col];
        xs[idx] = val;
    }
    __syncthreads();

    float qa[8] = {}, ka[8] = {}, va[8] = {};
    const float* xw = xs + (w * 8) * 64;
    #pragma unroll 4
    for (int d = 0; d < 64; ++d) {
        const float wq = Wq[d * 64 + e];
        const float wk = Wk[d * 64 + e];
        const float wv = Wv[d * 64 + e];
        #pragma unroll
        for (int i = 0; i < 8; ++i) {
            const float x = xw[i * 64 + d];   // LDS broadcast
            qa[i] = fmaf(x, wq, qa[i]);
            ka[i] = fmaf(x, wk, ka[i]);
            va[i] = fmaf(x, wv, va[i]);
        }
    }

    #pragma unroll
    for (int i = 0; i < 8; ++i) {
        const int r = r0 + w * 8 + i;
        if (r >= total) break;
        const bool is_map = r < n_map;
        // GLU: lanes 0..31 hold a=v[e], need b=v[e+32]
        const float vother = __shfl_xor(va[i], 32);
        const float sig = 1.0f / (1.0f + __builtin_amdgcn_exp2f(-vother * LOG2E));
        const float g = va[i] * sig; // valid for lanes e < 32

        if (is_map) {
            qbf[(size_t)r * 64 + e] = __float2bfloat16(qa[i] * IT);
            float qk = qa[i] * ka[i];
            #pragma unroll
            for (int off = 32; off; off >>= 1) qk += __shfl_xor(qk, off);
            if (e == 0) pself[r] = __builtin_amdgcn_exp2f(qk * IT);
            if (e < 32) gmT[(size_t)e * n_map + r] = g;   // transposed
        } else {
            const int j  = r - n_map;          // key index
            const int kb = j >> 5, jq = j & 31;
            {   // Kp: thread e holds K[j][d=e]
                const int c = e >> 4, h2 = (e >> 3) & 1, ii = e & 7;
                Kp[(size_t)kb * 2048 + c * 512 + (h2 * 32 + jq) * 8 + ii] =
                    __float2bfloat16(ka[i]);
            }
            if (e < 32) {  // Vp: thread e holds gated[key=j][vdim=e]
                const int h = jq >> 4, h3 = (jq >> 3) & 1, ii = jq & 7;
                Vp[(size_t)kb * 1024 + h * 512 + (h3 * 32 + e) * 8 + ii] =
                    __float2bfloat16(g);
            }
        }
    }
}

// -------------------------------------------------------------- attn ------
// grid = (n_map/256) * ks. Block: qb = bid>>kslog (8 q-tiles = 256 rows),
// slice = bid & (ks-1); wave w owns q-tile qb*8+w. Slice staged to LDS in
// 4-kb (24KB) chunks: copy, barrier, 4 barrier-free bodies, barrier.
// __launch_bounds__(512,8) targets 64 VGPR -> 4 blocks/CU (LDS allows 6).
// Swapped QK^T (Q pre-scaled by IT), O^T orientation, no-max softmax.
#define WAVES 8
__global__ __launch_bounds__(64 * WAVES, 8) void attn_partial(
    const __hip_bfloat16* __restrict__ qbf, const __hip_bfloat16* __restrict__ Kp,
    const __hip_bfloat16* __restrict__ Vp,
    __hip_bfloat16* __restrict__ oP, float* __restrict__ lP,
    int n_obs, int n_map, int kslog)
{
    const int tid  = threadIdx.x;
    const int w    = tid >> 6;
    const int lane = tid & 63;
    const int ql   = lane & 31;
    const int hi   = lane >> 5;
    const int qb   = blockIdx.x >> kslog;
    const int slice= blockIdx.x & ((1 << kslog) - 1);
    const int tileT= qb * WAVES + w;           // global q-tile index
    const int q    = tileT * 32 + ql;

    // 4-kb chunk staging: K 16KB | V 8KB
    __shared__ __align__(16) char kl[16384 + 8192];
    char* vl = kl + 16384;

    bf16x8 qf[4];
    {
        const __hip_bfloat16* qrow = qbf + (size_t)q * 64 + 8 * hi;
        #pragma unroll
        for (int c = 0; c < 4; ++c)
            qf[c] = *reinterpret_cast<const bf16x8*>(qrow + c * 16);
    }

    float lsumA = 0.0f, lsumB = 0.0f;
    f32x16 o = {};

    const int nkb      = (n_obs >> kslog) >> 5;   // key-blocks per slice
    const int kb_begin = slice * nkb;
    const char* Kb = (const char*)Kp;
    const char* Vb = (const char*)Vp;

    auto body = [&](const bf16x8 (&kf)[4], const bf16x8 (&vf)[2]) {
        f32x16 s = {};
        #pragma unroll
        for (int c = 0; c < 4; ++c)
            s = __builtin_amdgcn_mfma_f32_32x32x16_bf16(kf[c], qf[c], s, 0, 0, 0);
        float p[16];
        #pragma unroll
        for (int r = 0; r < 16; ++r) p[r] = __builtin_amdgcn_exp2f(s[r]);
        #pragma unroll
        for (int r = 0; r < 8; ++r) { lsumA += p[r]; lsumB += p[r + 8]; }
        union { u32 u[4]; bf16x8 v; } pb0, pb1;
        {
            u32 x0 = cvt_pk_bf16(p[0], p[1]);
            u32 x1 = cvt_pk_bf16(p[2], p[3]);
            u32 y0 = cvt_pk_bf16(p[4], p[5]);
            u32 y1 = cvt_pk_bf16(p[6], p[7]);
            permswap32(x0, y0);
            permswap32(x1, y1);
            pb0.u[0] = x0; pb0.u[1] = x1; pb0.u[2] = y0; pb0.u[3] = y1;
        }
        {
            u32 x0 = cvt_pk_bf16(p[8],  p[9]);
            u32 x1 = cvt_pk_bf16(p[10], p[11]);
            u32 y0 = cvt_pk_bf16(p[12], p[13]);
            u32 y1 = cvt_pk_bf16(p[14], p[15]);
            permswap32(x0, y0);
            permswap32(x1, y1);
            pb1.u[0] = x0; pb1.u[1] = x1; pb1.u[2] = y0; pb1.u[3] = y1;
        }
        o = __builtin_amdgcn_mfma_f32_32x32x16_bf16(vf[0], pb0.v, o, 0, 0, 0);
        o = __builtin_amdgcn_mfma_f32_32x32x16_bf16(vf[1], pb1.v, o, 0, 0, 0);
    };

    // ---- 4-kb chunks: stage 24KB, barrier, 4 bodies/wave ----
    for (int c0 = 0; c0 < nkb; c0 += 4) {
        if (c0) __syncthreads();               // prior chunk's reads done
        const char* Ks = Kb + (size_t)(kb_begin + c0) * 4096;
        const char* Vs = Vb + (size_t)(kb_begin + c0) * 2048;
        #pragma unroll
        for (int i = 0; i < 2; ++i) {          // K: 1024 x 16B
            const int idx = i * 512 + tid;
            *reinterpret_cast<uint4*>(kl + idx * 16) =
                *reinterpret_cast<const uint4*>(Ks + idx * 16);
        }
        {                                      // V: 512 x 16B
            *reinterpret_cast<uint4*>(vl + tid * 16) =
                *reinterpret_cast<const uint4*>(Vs + tid * 16);
        }
        __syncthreads();

        #pragma unroll 2
        for (int kb = 0; kb < 4; ++kb) {
            bf16x8 kf[4], vf[2];
            const char* kbp = kl + kb * 4096 + lane * 16;
            #pragma unroll
            for (int c = 0; c < 4; ++c)
                kf[c] = *reinterpret_cast<const bf16x8*>(kbp + c * 1024);
            const char* vbp = vl + kb * 2048 + lane * 16;
            vf[0] = *reinterpret_cast<const bf16x8*>(vbp);
            vf[1] = *reinterpret_cast<const bf16x8*>(vbp + 1024);
            body(kf, vf);
        }
    }

    float lsum = lsumA + lsumB;
    lsum += __shfl_xor(lsum, 32);
    if (hi == 0) lP[(size_t)slice * n_map + tileT * 32 + ql] = lsum;
    __hip_bfloat16* ob = oP + ((size_t)slice * (n_map >> 5) + tileT) * 1024;
    #pragma unroll
    for (int r = 0; r < 16; ++r) {
        const int vr = (r & 3) + 8 * (r >> 2) + 4 * hi;
        ob[vr * 32 + ql] = __float2bfloat16(o[r]);
    }
}

// --------------------------------------------------------- combine_epi ----
// grid = ntiles; 256 thr = 4 waves. Fused: vectorized slice-reduction of
// oP (uint2 = 4 bf16 per slice, 4 elems/thread, unroll-4 MLP) + self term
// (coalesced pself/gmT) -> LDS aggT; parallel lP reduce; Wo/residual/LN.
__global__ __launch_bounds__(256) void combine_epi(
    const __hip_bfloat16* __restrict__ oP, const float* __restrict__ lP,
    const float* __restrict__ pself, const float* __restrict__ gmT,
    const float* __restrict__ map_code, const float* __restrict__ Wo,
    const float* __restrict__ bo, const float* __restrict__ gamma,
    const float* __restrict__ beta, float* __restrict__ out,
    int n_map, int ks)
{
    const int tid  = threadIdx.x;
    const int w    = tid >> 6;
    const int lane = tid & 63;
    const int T    = blockIdx.x;
    const int q0   = T * 32;
    const int ntiles = n_map >> 5;

    __shared__ float aggT[32][33];
    __shared__ float lsumL[8][32];
    __shared__ float invS[32];

    // parallel lP reduction: group g = tid>>5 handles slices g, g+8, ...
    {
        const int g  = tid >> 5;
        const int qq = tid & 31;
        float part = 0.0f;
        for (int s = g; s < ks; s += 8)
            part += lP[(size_t)s * n_map + q0 + qq];
        lsumL[g][qq] = part;
    }

    // slice-reduce 4 consecutive elements per thread
    {
        const int e0  = tid * 4;
        const int v   = e0 >> 5;
        const int qq0 = e0 & 31;
        float a[4];
        {
            const float4 ps = *reinterpret_cast<const float4*>(pself + q0 + qq0);
            const float4 g4 = *reinterpret_cast<const float4*>(
                gmT + (size_t)v * n_map + q0 + qq0);
            a[0] = ps.x * g4.x; a[1] = ps.y * g4.y;
            a[2] = ps.z * g4.z; a[3] = ps.w * g4.w;
        }
        const __hip_bfloat16* ob = oP + (size_t)T * 1024 + e0;
        const size_t sstride = (size_t)ntiles * 1024;
        #pragma unroll 4
        for (int s = 0; s < ks; ++s) {
            const uint2 u = *reinterpret_cast<const uint2*>(ob + s * sstride);
            a[0] += __uint_as_float(u.x << 16);
            a[1] += __uint_as_float(u.x & 0xffff0000u);
            a[2] += __uint_as_float(u.y << 16);
            a[3] += __uint_as_float(u.y & 0xffff0000u);
        }
        aggT[v][qq0 + 0] = a[0]; aggT[v][qq0 + 1] = a[1];
        aggT[v][qq0 + 2] = a[2]; aggT[v][qq0 + 3] = a[3];
    }
    __syncthreads();
    if (tid < 32) {
        float l = pself[q0 + tid];
        #pragma unroll
        for (int g = 0; g < 8; ++g) l += lsumL[g][tid];
        invS[tid] = 1.0f / l;
    }
    __syncthreads();

    float wo[32];
    #pragma unroll
    for (int vv = 0; vv < 32; ++vv) wo[vv] = Wo[vv * 64 + lane];
    const float bo_e = bo[lane], ga = gamma[lane], be = beta[lane];

    #pragma unroll
    for (int i = 0; i < 8; ++i) {
        const int qq = w * 8 + i;
        float dot = 0.0f;
        #pragma unroll
        for (int vv = 0; vv < 32; ++vv)
            dot = fmaf(aggT[vv][qq], wo[vv], dot); // LDS broadcast reads
        float acc = dot * invS[qq] + bo_e + map_code[(size_t)(q0 + qq) * 64 + lane];
        float mu = acc;
        #pragma unroll
        for (int off = 32; off; off >>= 1) mu += __shfl_xor(mu, off);
        mu *= (1.0f / 64.0f);
        const float dc = acc - mu;
        float var = dc * dc;
        #pragma unroll
        for (int off = 32; off; off >>= 1) var += __shfl_xor(var, off);
        var *= (1.0f / 64.0f);
        out[(size_t)(q0 + qq) * 64 + lane] =
            dc * rsqrtf(var + 1e-6f) * ga + be;
    }
}

// -------------------------------------------------------------- launch ----
extern "C" void kernel_launch(void* const* d_in, const int* in_sizes, int n_in,
                              void* d_out, int out_size, void* d_ws, size_t ws_size,
                              hipStream_t stream) {
    const float* map_code = (const float*)d_in[0];
    const float* obs_code = (const float*)d_in[1];
    const float* Wq  = (const float*)d_in[2];
    const float* Wk  = (const float*)d_in[3];
    const float* Wv  = (const float*)d_in[4];
    const float* Wo  = (const float*)d_in[5];
    const float* bo  = (const float*)d_in[6];
    const float* gam = (const float*)d_in[7];
    const float* bet = (const float*)d_in[8];
    const int n_map = in_sizes[0] / 64;   // 16384
    const int n_obs = in_sizes[1] / 64;   // 8192
    const int ntiles = n_map / 32;        // 512

    char* ws = (char*)d_ws;
    __hip_bfloat16* qbf = (__hip_bfloat16*)ws; ws += (size_t)n_map * 64 * 2;
    __hip_bfloat16* Kp  = (__hip_bfloat16*)ws; ws += (size_t)n_obs * 64 * 2;
    __hip_bfloat16* Vp  = (__hip_bfloat16*)ws; ws += (size_t)n_obs * 32 * 2;
    float* pself        = (float*)ws;          ws += (size_t)n_map * 4;
    float* gmT          = (float*)ws;          ws += (size_t)n_map * 32 * 4;
    const size_t base   = (size_t)(ws - (char*)d_ws);
    // per-slice partial cost: oP (n_map*32 bf16) + lP (n_map f32)
    const size_t per_slice = (size_t)n_map * 32 * 2 + (size_t)n_map * 4;
    int kslog = 5;   // ks=32 -> slice = 256 keys, staged in 4-kb LDS chunks
    while (kslog > 0 && base + ((size_t)1 << kslog) * per_slice > ws_size)
        --kslog;
    const int ks = 1 << kslog;
    __hip_bfloat16* oP = (__hip_bfloat16*)ws; ws += (size_t)ks * n_map * 32 * 2;
    float* lP = (float*)ws;  // ks * n_map * 4

    const int total = n_map + n_obs;
    prep_kernel<<<(total + 31) / 32, 256, 0, stream>>>(
        map_code, obs_code, Wq, Wk, Wv, qbf, Kp, Vp, pself, gmT,
        n_map, n_obs);
    attn_partial<<<(n_map / 256) * ks, 64 * WAVES, 0, stream>>>(
        qbf, Kp, Vp, oP, lP, n_obs, n_map, kslog);
    combine_epi<<<ntiles, 256, 0, stream>>>(
        oP, lP, pself, gmT, map_code, Wo, bo, gam, bet,
        (float*)d_out, n_map, ks);
}